// Round 8
// baseline (128.736 us; speedup 1.0000x reference)
//
#include <hip/hip_runtime.h>
#include <stdint.h>

typedef unsigned short u16;
typedef unsigned int u32;
typedef u32 u32x4 __attribute__((ext_vector_type(4)));
typedef __bf16 bf16x8 __attribute__((ext_vector_type(8)));
typedef __bf16 bf16x4 __attribute__((ext_vector_type(4)));
typedef float f32x4 __attribute__((ext_vector_type(4)));
typedef float f32x16 __attribute__((ext_vector_type(16)));

// fp32 -> bf16 round-to-nearest-even
__device__ __forceinline__ u16 f2bf(float f) {
  u32 u = __float_as_uint(f);
  u = (u + 0x7fffu + ((u >> 16) & 1u)) >> 16;
  return (u16)u;
}

// async global->LDS, 16B per lane; lds base must be wave-uniform (HW adds lane*16)
__device__ __forceinline__ void gload16(const void* g, void* l) {
  __builtin_amdgcn_global_load_lds(
      (const __attribute__((address_space(1))) void*)g,
      (__attribute__((address_space(3))) void*)l, 16, 0, 0);
}

// pack two f32 -> u32 of two bf16 (lo = a, hi = b)
__device__ __forceinline__ u32 cvtpk(float a, float b) {
  u32 r;
  asm("v_cvt_pk_bf16_f32 %0, %1, %2" : "=v"(r) : "v"(a), "v"(b));
  return r;
}

// v_permlane32_swap_b32: x[32:63] <-> y[0:31]. After: x = word for all lanes'
// "low-source" role, y = "high-source" role (see P-frag derivation in attn_k).
__device__ __forceinline__ void plswap(u32& x, u32& y) {
  asm volatile("v_permlane32_swap_b32 %0, %1" : "+v"(x), "+v"(y));
}

// ---------------- fp32 -> bf16 convert (query/key/value) ----------------
__global__ __launch_bounds__(256) void cvt_qkv(
    const float* __restrict__ q, const float* __restrict__ k,
    const float* __restrict__ v, u16* __restrict__ dst) {
  const float* s = (blockIdx.y == 0) ? q : (blockIdx.y == 1) ? k : v;
  u16* d = dst + (size_t)blockIdx.y * 4194304u;
  int e = (blockIdx.x * 256 + threadIdx.x) * 8;
  float4 a = *(const float4*)(s + e);
  float4 b = *(const float4*)(s + e + 4);
  uint4 o;
  o.x = (u32)f2bf(a.x) | ((u32)f2bf(a.y) << 16);
  o.y = (u32)f2bf(a.z) | ((u32)f2bf(a.w) << 16);
  o.z = (u32)f2bf(b.x) | ((u32)f2bf(b.y) << 16);
  o.w = (u32)f2bf(b.z) | ((u32)f2bf(b.w) << 16);
  *(uint4*)(d + e) = o;
}

// ---------------- W [1024][1024] fp32 -> W^T bf16 ----------------
__global__ __launch_bounds__(512) void trans_w(
    const float* __restrict__ w0, const float* __restrict__ w1,
    const float* __restrict__ w2, const float* __restrict__ w3,
    u16* __restrict__ wt) {
  const float* W = (blockIdx.z == 0) ? w0 : (blockIdx.z == 1) ? w1
                   : (blockIdx.z == 2) ? w2 : w3;
  u16* Wt = wt + (size_t)blockIdx.z * 1048576u;
  __shared__ float tile[64][65];
  int x0 = blockIdx.x * 64, y0 = blockIdx.y * 64;
  int tx = threadIdx.x, ty = threadIdx.y;
#pragma unroll
  for (int j = 0; j < 8; ++j)
    tile[ty + j * 8][tx] = W[(size_t)(y0 + ty + j * 8) * 1024 + x0 + tx];
  __syncthreads();
#pragma unroll
  for (int j = 0; j < 8; ++j)
    Wt[(size_t)(x0 + ty + j * 8) * 1024 + y0 + tx] = f2bf(tile[tx][ty + j * 8]);
}

// ---------------- merged projection GEMM (Q, K, V^T) ----------------
// z=0: Qb = (Xq @ Wq + bq) * qsc        [4096][1024]
// z=1: Kb =  Xk @ Wk + bk               [4096][1024]
// z=2: VtG = (Wv^T . Xv^T) + bv(row)    [1024][4096]
// R6 form (two-barrier): explicit dbuf regressed in R7 (compiler drains vmcnt
// before ds_read due to LDS aliasing conservatism) — do not re-add.
__global__ __launch_bounds__(256, 2) void gemm_proj(
    const u16* __restrict__ Xb, const u16* __restrict__ Wt,
    const float* __restrict__ bqp, const float* __restrict__ bkp,
    const float* __restrict__ bvp,
    u16* __restrict__ Qb, u16* __restrict__ Kb, u16* __restrict__ VtG,
    float qsc) {
  const int z = blockIdx.z;
  const u16 *A, *Bt;
  const float* bias;
  u16* C;
  int N, bm, bn;
  float osc = 1.f;
  bool rowb = false;
  if (z < 2) {
    A = Xb + (size_t)z * 4194304u;
    Bt = Wt + (size_t)z * 1048576u;
    bias = z ? bkp : bqp;
    C = z ? Kb : Qb;
    N = 1024;
    bm = blockIdx.x * 128;
    bn = blockIdx.y * 128;
    if (z == 0) osc = qsc;
  } else {
    A = Wt + 2u * 1048576u;
    Bt = Xb + 2u * 4194304u;
    bias = bvp;
    C = VtG;
    N = 4096;
    bm = blockIdx.y * 128;
    bn = blockIdx.x * 128;
    rowb = true;
  }

  __shared__ __align__(16) u16 ldsA[128 * 64];
  __shared__ __align__(16) u16 ldsB[128 * 64];

  const int tid = threadIdx.x;
  const int lane = tid & 63, wv = tid >> 6;
  const int wr = wv >> 1, wc = wv & 1;
  const int l15 = lane & 15, l4 = lane >> 4;

  const f32x4 zero4 = {0.f, 0.f, 0.f, 0.f};
  f32x4 acc[4][4];
#pragma unroll
  for (int i = 0; i < 4; ++i)
#pragma unroll
    for (int j = 0; j < 4; ++j) acc[i][j] = zero4;

  for (int kt = 0; kt < 16; ++kt) {
    __syncthreads();
#pragma unroll
    for (int g = 0; g < 4; ++g) {
      int p = g * 256 + tid;
      int row = p >> 3;
      int ss = (p & 7) ^ (row & 7);
      gload16(A + (size_t)(bm + row) * 1024 + kt * 64 + ss * 8,
              (char*)ldsA + (g * 256 + wv * 64) * 16);
    }
#pragma unroll
    for (int g = 0; g < 4; ++g) {
      int p = g * 256 + tid;
      int row = p >> 3;
      int ss = (p & 7) ^ (row & 7);
      gload16(Bt + (size_t)(bn + row) * 1024 + kt * 64 + ss * 8,
              (char*)ldsB + (g * 256 + wv * 64) * 16);
    }
    __syncthreads();

    bf16x8 af[4][2], bfr[4][2];
#pragma unroll
    for (int mf = 0; mf < 4; ++mf) {
      int row = wr * 64 + mf * 16 + l15;
#pragma unroll
      for (int ks = 0; ks < 2; ++ks) {
        int byt = row * 128 + ((ks * 64 + l4 * 16) ^ ((row & 7) << 4));
        af[mf][ks] = *(const bf16x8*)((const char*)ldsA + byt);
      }
    }
#pragma unroll
    for (int nf = 0; nf < 4; ++nf) {
      int row = wc * 64 + nf * 16 + l15;
#pragma unroll
      for (int ks = 0; ks < 2; ++ks) {
        int byt = row * 128 + ((ks * 64 + l4 * 16) ^ ((row & 7) << 4));
        bfr[nf][ks] = *(const bf16x8*)((const char*)ldsB + byt);
      }
    }
#pragma unroll
    for (int mf = 0; mf < 4; ++mf)
#pragma unroll
      for (int nf = 0; nf < 4; ++nf) {
        acc[mf][nf] = __builtin_amdgcn_mfma_f32_16x16x32_bf16(
            af[mf][0], bfr[nf][0], acc[mf][nf], 0, 0, 0);
        acc[mf][nf] = __builtin_amdgcn_mfma_f32_16x16x32_bf16(
            af[mf][1], bfr[nf][1], acc[mf][nf], 0, 0, 0);
      }
  }

  float bcol[4];
  if (!rowb) {
#pragma unroll
    for (int nf = 0; nf < 4; ++nf)
      bcol[nf] = bias[bn + wc * 64 + nf * 16 + l15];
  }
#pragma unroll
  for (int mf = 0; mf < 4; ++mf) {
#pragma unroll
    for (int i = 0; i < 4; ++i) {
      int r = bm + wr * 64 + mf * 16 + l4 * 4 + i;
      float br = rowb ? bias[r] : 0.f;
#pragma unroll
      for (int nf = 0; nf < 4; ++nf) {
        int c = bn + wc * 64 + nf * 16 + l15;
        float val = (acc[mf][nf][i] + (rowb ? br : bcol[nf])) * osc;
        C[(size_t)r * N + c] = f2bf(val);
      }
    }
  }
}

// ---------------- final GEMM: out = ctx @ Wo^T' + bo (fp32) ----------------
__global__ __launch_bounds__(256, 2) void gemm_out(
    const u16* __restrict__ A, const u16* __restrict__ Bt,
    const float* __restrict__ bias, float* __restrict__ C) {
  __shared__ __align__(16) u16 ldsA[128 * 64];
  __shared__ __align__(16) u16 ldsB[128 * 64];

  const int tid = threadIdx.x;
  const int lane = tid & 63, wv = tid >> 6;
  const int wr = wv >> 1, wc = wv & 1;
  const int l15 = lane & 15, l4 = lane >> 4;
  const int bm = blockIdx.x * 128, bn = blockIdx.y * 128;

  const f32x4 zero4 = {0.f, 0.f, 0.f, 0.f};
  f32x4 acc[4][4];
#pragma unroll
  for (int i = 0; i < 4; ++i)
#pragma unroll
    for (int j = 0; j < 4; ++j) acc[i][j] = zero4;

  for (int kt = 0; kt < 16; ++kt) {
    __syncthreads();
#pragma unroll
    for (int g = 0; g < 4; ++g) {
      int p = g * 256 + tid;
      int row = p >> 3;
      int ss = (p & 7) ^ (row & 7);
      gload16(A + (size_t)(bm + row) * 1024 + kt * 64 + ss * 8,
              (char*)ldsA + (g * 256 + wv * 64) * 16);
    }
#pragma unroll
    for (int g = 0; g < 4; ++g) {
      int p = g * 256 + tid;
      int row = p >> 3;
      int ss = (p & 7) ^ (row & 7);
      gload16(Bt + (size_t)(bn + row) * 1024 + kt * 64 + ss * 8,
              (char*)ldsB + (g * 256 + wv * 64) * 16);
    }
    __syncthreads();

    bf16x8 af[4][2], bfr[4][2];
#pragma unroll
    for (int mf = 0; mf < 4; ++mf) {
      int row = wr * 64 + mf * 16 + l15;
#pragma unroll
      for (int ks = 0; ks < 2; ++ks) {
        int byt = row * 128 + ((ks * 64 + l4 * 16) ^ ((row & 7) << 4));
        af[mf][ks] = *(const bf16x8*)((const char*)ldsA + byt);
      }
    }
#pragma unroll
    for (int nf = 0; nf < 4; ++nf) {
      int row = wc * 64 + nf * 16 + l15;
#pragma unroll
      for (int ks = 0; ks < 2; ++ks) {
        int byt = row * 128 + ((ks * 64 + l4 * 16) ^ ((row & 7) << 4));
        bfr[nf][ks] = *(const bf16x8*)((const char*)ldsB + byt);
      }
    }
#pragma unroll
    for (int mf = 0; mf < 4; ++mf)
#pragma unroll
      for (int nf = 0; nf < 4; ++nf) {
        acc[mf][nf] = __builtin_amdgcn_mfma_f32_16x16x32_bf16(
            af[mf][0], bfr[nf][0], acc[mf][nf], 0, 0, 0);
        acc[mf][nf] = __builtin_amdgcn_mfma_f32_16x16x32_bf16(
            af[mf][1], bfr[nf][1], acc[mf][nf], 0, 0, 0);
      }
  }

  float bcol[4];
#pragma unroll
  for (int nf = 0; nf < 4; ++nf)
    bcol[nf] = bias[bn + wc * 64 + nf * 16 + l15];
#pragma unroll
  for (int mf = 0; mf < 4; ++mf) {
#pragma unroll
    for (int i = 0; i < 4; ++i) {
      int r = bm + wr * 64 + mf * 16 + l4 * 4 + i;
#pragma unroll
      for (int nf = 0; nf < 4; ++nf) {
        int c = bn + wc * 64 + nf * 16 + l15;
        C[(size_t)r * 1024 + c] = acc[mf][nf][i] + bcol[nf];
      }
    }
  }
}

// ---------------- causal flash attention: 32x32x16 MFMA, in-register P ------
// Q,K: [B*S][1024] bf16, Q pre-scaled by log2(e)/sqrt(2048). Vt: [d][B*S].
// Grid 1024=(32,32), 128-thread blocks (2 waves x 32 q-rows = 64 q/block).
// XCD-pinned (id%8), 4 bh columns/XCD, qt descending. KVBLK=64, dbuf staging.
// Swapped QK^T on 32x32x16: lane holds S^T[kv][q=lane&31] where
// kv = kh*32 + (r&3)+8*(r>>2)+4*(lane>>5). Softmax per-lane + 1 shfl_xor(32).
// P stays in registers: PV B-frag[ks] words built from cvt_pk pairs c0..c3
// (c_n = pack(p[8s+2n], p[8s+2n+1]), s=ks&1) + permlane32_swap(c0,c2),(c1,c3)
// -> frag = {c0',c1',c2',c3'} for both lane halves simultaneously.
__global__ __launch_bounds__(128, 2) void attn_k(
    const u16* __restrict__ Q, const u16* __restrict__ Kb,
    const u16* __restrict__ Vt, u16* __restrict__ ctx) {
  const int id = blockIdx.x + (blockIdx.y << 5);
  const int xcd = id & 7;
  const int kk = id >> 3;               // 0..127
  const int bh = xcd * 4 + (kk & 3);    // 4 bh columns per XCD
  const int qt = 31 - (kk >> 2);        // q-tile (64 rows), longest first
  const int b = bh >> 4, h = bh & 15;
  const int tid = threadIdx.x;          // 0..127
  const int lane = tid & 63, wv = tid >> 6;   // 2 waves
  const int l31 = lane & 31, l4b = lane >> 5; // lane half

  __shared__ __align__(16) u16 Kt[2][64 * 64];  // [kv][d], swizzled
  __shared__ __align__(16) u16 Vl[2][64 * 64];  // [d][kv], swizzled

  const u16* KB = Kb + (size_t)(b * 2048) * 1024 + h * 64;
  const u16* VB = Vt + (size_t)(h * 64) * 4096 + b * 2048;

  // Q B-frags: B[k=ks*16+l4b*8+e][col=q=l31]
  const int qrow = qt * 64 + wv * 32 + l31;
  const u16* qp = Q + (size_t)(b * 2048 + qrow) * 1024 + h * 64;
  bf16x8 qf[4];
#pragma unroll
  for (int ks = 0; ks < 4; ++ks)
    qf[ks] = *(const bf16x8*)(qp + ks * 16 + l4b * 8);

  const f32x16 z16 = {0.f, 0.f, 0.f, 0.f, 0.f, 0.f, 0.f, 0.f,
                      0.f, 0.f, 0.f, 0.f, 0.f, 0.f, 0.f, 0.f};
  f32x16 o0 = z16, o1 = z16;  // O^T[d][q=l31], d 0..31 / 32..63
  float m = -1e30f, lsum = 0.f;

  auto issueKV = [&](int jt, int bufi) {
    const u16* kb = KB + (size_t)(jt * 64) * 1024;
#pragma unroll
    for (int g = 0; g < 4; ++g) {
      int p = g * 128 + tid;
      int row = p >> 3;
      int ss = (p & 7) ^ (row & 7);
      gload16(kb + (size_t)row * 1024 + ss * 8,
              (char*)(&Kt[bufi][0]) + (g * 128 + wv * 64) * 16);
    }
#pragma unroll
    for (int g = 0; g < 4; ++g) {
      int p = g * 128 + tid;
      int d = p >> 3;
      int ss = (p & 7) ^ (d & 7);
      gload16(VB + (size_t)d * 4096 + jt * 64 + ss * 8,
              (char*)(&Vl[bufi][0]) + (g * 128 + wv * 64) * 16);
    }
  };

  const int swz = (l31 & 7) << 4;  // row-XOR swizzle term (row&7 == l31&7)

  issueKV(0, 0);
  for (int j = 0; j <= qt; ++j) {
    const int cur = j & 1;
    __syncthreads();  // own-vmcnt drain -> tile j resident; other buffer free
    if (j < qt) issueKV(j + 1, cur ^ 1);

    // QK^T: S^T tiles p0 (kv 0..31), p1 (kv 32..63); A=K-frag, B=Q-frag
    f32x16 p0 = z16, p1 = z16;
    __builtin_amdgcn_s_setprio(1);
#pragma unroll
    for (int ks = 0; ks < 4; ++ks) {
      const char* k0r = (const char*)&Kt[cur][0] + l31 * 128;
      const char* k1r = (const char*)&Kt[cur][0] + (32 + l31) * 128;
      bf16x8 k0 = *(const bf16x8*)(k0r + ((ks * 32 + l4b * 16) ^ swz));
      bf16x8 k1 = *(const bf16x8*)(k1r + ((ks * 32 + l4b * 16) ^ swz));
      p0 = __builtin_amdgcn_mfma_f32_32x32x16_bf16(k0, qf[ks], p0, 0, 0, 0);
      p1 = __builtin_amdgcn_mfma_f32_32x32x16_bf16(k1, qf[ks], p1, 0, 0, 0);
    }
    __builtin_amdgcn_s_setprio(0);

    if (j == qt) {  // causal mask on diagonal tile
#pragma unroll
      for (int r = 0; r < 16; ++r) {
        int kvl = (r & 3) + 8 * (r >> 2) + 4 * l4b;
        int kv = j * 64 + kvl;
        if (kv > qrow) p0[r] = -1e30f;
        if (kv + 32 > qrow) p1[r] = -1e30f;
      }
    }

    // row max: in-register tree + one cross-half exchange
    float a0 = fmaxf(fmaxf(p0[0], p0[1]), fmaxf(p0[2], p0[3]));
    float a1 = fmaxf(fmaxf(p0[4], p0[5]), fmaxf(p0[6], p0[7]));
    float a2 = fmaxf(fmaxf(p0[8], p0[9]), fmaxf(p0[10], p0[11]));
    float a3 = fmaxf(fmaxf(p0[12], p0[13]), fmaxf(p0[14], p0[15]));
    float b0 = fmaxf(fmaxf(p1[0], p1[1]), fmaxf(p1[2], p1[3]));
    float b1 = fmaxf(fmaxf(p1[4], p1[5]), fmaxf(p1[6], p1[7]));
    float b2 = fmaxf(fmaxf(p1[8], p1[9]), fmaxf(p1[10], p1[11]));
    float b3 = fmaxf(fmaxf(p1[12], p1[13]), fmaxf(p1[14], p1[15]));
    float rm = fmaxf(fmaxf(fmaxf(a0, a1), fmaxf(a2, a3)),
                     fmaxf(fmaxf(b0, b1), fmaxf(b2, b3)));
    rm = fmaxf(rm, __shfl_xor(rm, 32, 64));

    // defer-max (THR=8 in log2 domain): rescale only when max grew
    if (!__all(rm - m <= 8.0f)) {
      float mn = fmaxf(m, rm);
      float ce = exp2f(m - mn);  // per-lane (q = l31): no broadcast needed
      m = mn;
      lsum *= ce;
#pragma unroll
      for (int r = 0; r < 16; ++r) {
        o0[r] *= ce;
        o1[r] *= ce;
      }
    }

    // P = exp2(S - m); row sum
    float rs = 0.f;
#pragma unroll
    for (int r = 0; r < 16; ++r) {
      float e0 = exp2f(p0[r] - m);
      float e1 = exp2f(p1[r] - m);
      p0[r] = e0;
      p1[r] = e1;
      rs += e0 + e1;
    }
    rs += __shfl_xor(rs, 32, 64);
    lsum += rs;

    // build PV B-frags in registers (16 cvt_pk + 8 permlane32_swap)
    bf16x8 pf[4];
#pragma unroll
    for (int ks = 0; ks < 4; ++ks) {
      const int s = ks & 1;
      u32 c0, c1, c2, c3;
      if (ks < 2) {
        c0 = cvtpk(p0[8 * s + 0], p0[8 * s + 1]);
        c1 = cvtpk(p0[8 * s + 2], p0[8 * s + 3]);
        c2 = cvtpk(p0[8 * s + 4], p0[8 * s + 5]);
        c3 = cvtpk(p0[8 * s + 6], p0[8 * s + 7]);
      } else {
        c0 = cvtpk(p1[8 * s + 0], p1[8 * s + 1]);
        c1 = cvtpk(p1[8 * s + 2], p1[8 * s + 3]);
        c2 = cvtpk(p1[8 * s + 4], p1[8 * s + 5]);
        c3 = cvtpk(p1[8 * s + 6], p1[8 * s + 7]);
      }
      plswap(c0, c2);
      plswap(c1, c3);
      u32x4 w = {c0, c1, c2, c3};
      pf[ks] = __builtin_bit_cast(bf16x8, w);
    }

    // O^T += V^T P  (A = V^T-frag rows d, B = P-frag)
    __builtin_amdgcn_s_setprio(1);
#pragma unroll
    for (int ks = 0; ks < 4; ++ks) {
      const char* v0r = (const char*)&Vl[cur][0] + l31 * 128;
      const char* v1r = (const char*)&Vl[cur][0] + (32 + l31) * 128;
      bf16x8 v0 = *(const bf16x8*)(v0r + ((ks * 32 + l4b * 16) ^ swz));
      bf16x8 v1 = *(const bf16x8*)(v1r + ((ks * 32 + l4b * 16) ^ swz));
      o0 = __builtin_amdgcn_mfma_f32_32x32x16_bf16(v0, pf[ks], o0, 0, 0, 0);
      o1 = __builtin_amdgcn_mfma_f32_32x32x16_bf16(v1, pf[ks], o1, 0, 0, 0);
    }
    __builtin_amdgcn_s_setprio(0);
  }

  // normalize + store ctx (bf16, [b*2048+q][h*64+d]); per-lane q = l31
  float rcp = 1.f / lsum;
  u16* cb = ctx + (size_t)(b * 2048 + qrow) * 1024 + h * 64;
#pragma unroll
  for (int g = 0; g < 4; ++g) {
    {
      int d = 8 * g + 4 * l4b;
      f32x4 t = {o0[4 * g + 0] * rcp, o0[4 * g + 1] * rcp,
                 o0[4 * g + 2] * rcp, o0[4 * g + 3] * rcp};
      *(bf16x4*)(cb + d) = __builtin_convertvector(t, bf16x4);
    }
    {
      int d = 32 + 8 * g + 4 * l4b;
      f32x4 t = {o1[4 * g + 0] * rcp, o1[4 * g + 1] * rcp,
                 o1[4 * g + 2] * rcp, o1[4 * g + 3] * rcp};
      *(bf16x4*)(cb + d) = __builtin_convertvector(t, bf16x4);
    }
  }
}

// ---------------- launch ----------------
extern "C" void kernel_launch(void* const* d_in, const int* in_sizes, int n_in,
                              void* d_out, int out_size, void* d_ws,
                              size_t ws_size, hipStream_t stream) {
  const float* q  = (const float*)d_in[0];
  const float* k  = (const float*)d_in[1];
  const float* v  = (const float*)d_in[2];
  const float* Wq = (const float*)d_in[3];
  const float* bq = (const float*)d_in[4];
  const float* Wk = (const float*)d_in[5];
  const float* bk = (const float*)d_in[6];
  const float* Wv = (const float*)d_in[7];
  const float* bv = (const float*)d_in[8];
  const float* Wo = (const float*)d_in[9];
  const float* bo = (const float*)d_in[10];

  // workspace layout (40 MiB):
  //   [0,24M):   Xb = bf16(query|key|value); first 8 MiB reused later as ctx
  //   [24M,32M): Wt = bf16 W^T for q,k,v,o
  //   [32M,40M): VtG = V^T bf16 [1024][4096]
  // d_out (16 MiB) doubles as Qb|Kb bf16 scratch until the final GEMM
  // fully overwrites it with fp32 output (deterministic each call).
  char* ws = (char*)d_ws;
  u16* Xb  = (u16*)ws;
  u16* Wt  = (u16*)(ws + 25165824);
  u16* VtG = (u16*)(ws + 33554432);
  u16* ctx = Xb;
  u16* Qb  = (u16*)d_out;
  u16* Kb  = Qb + 4194304;

  const float SC2A = 0.0318793585f;  // log2(e)/sqrt(2048), folded into Q

  cvt_qkv<<<dim3(2048, 3), 256, 0, stream>>>(q, k, v, Xb);
  trans_w<<<dim3(16, 16, 4), dim3(64, 8), 0, stream>>>(Wq, Wk, Wv, Wo, Wt);
  gemm_proj<<<dim3(32, 8, 3), 256, 0, stream>>>(Xb, Wt, bq, bk, bv, Qb, Kb,
                                                VtG, SC2A);
  attn_k<<<dim3(32, 32), 128, 0, stream>>>(Qb, Kb, VtG, ctx);
  gemm_out<<<dim3(32, 8), 256, 0, stream>>>(ctx, Wt + 3 * 1048576, bo,
                                            (float*)d_out);
}

// Round 9
// 114.197 us; speedup vs baseline: 1.1273x; 1.1273x over previous
//
#include <hip/hip_runtime.h>
#include <stdint.h>

typedef unsigned short u16;
typedef unsigned int u32;
typedef __bf16 bf16x8 __attribute__((ext_vector_type(8)));
typedef __bf16 bf16x4 __attribute__((ext_vector_type(4)));
typedef float f32x4 __attribute__((ext_vector_type(4)));

// fp32 -> bf16 round-to-nearest-even
__device__ __forceinline__ u16 f2bf(float f) {
  u32 u = __float_as_uint(f);
  u = (u + 0x7fffu + ((u >> 16) & 1u)) >> 16;
  return (u16)u;
}

// async global->LDS, 16B per lane; lds base must be wave-uniform (HW adds lane*16)
__device__ __forceinline__ void gload16(const void* g, void* l) {
  __builtin_amdgcn_global_load_lds(
      (const __attribute__((address_space(1))) void*)g,
      (__attribute__((address_space(3))) void*)l, 16, 0, 0);
}

// ---------------- merged prep: fp32->bf16 cvt (q,k,v) + W^T cvt ----------
// Blocks [0,6144): convert query|key|value (2048 blocks each, 2048 floats/blk)
// Blocks [6144,7168): transpose+convert Wq,Wk,Wv,Wo (256 blocks each, 64x64)
__global__ __launch_bounds__(256) void prep_k(
    const float* __restrict__ q, const float* __restrict__ k,
    const float* __restrict__ v, u16* __restrict__ dst,
    const float* __restrict__ w0, const float* __restrict__ w1,
    const float* __restrict__ w2, const float* __restrict__ w3,
    u16* __restrict__ wt) {
  const int id = blockIdx.x;
  if (id < 6144) {
    const int y = id >> 11;          // 0..2 -> q,k,v
    const int x = id & 2047;
    const float* s = (y == 0) ? q : (y == 1) ? k : v;
    u16* d = dst + (size_t)y * 4194304u;
    int e = (x * 256 + threadIdx.x) * 8;
    float4 a = *(const float4*)(s + e);
    float4 b = *(const float4*)(s + e + 4);
    uint4 o;
    o.x = (u32)f2bf(a.x) | ((u32)f2bf(a.y) << 16);
    o.y = (u32)f2bf(a.z) | ((u32)f2bf(a.w) << 16);
    o.z = (u32)f2bf(b.x) | ((u32)f2bf(b.y) << 16);
    o.w = (u32)f2bf(b.z) | ((u32)f2bf(b.w) << 16);
    *(uint4*)(d + e) = o;
    return;
  }
  // transpose path
  __shared__ float tile[64][65];
  const int t = id - 6144;
  const int z = t >> 8;            // 0..3 -> Wq,Wk,Wv,Wo
  const int rem = t & 255;
  const int x0 = (rem & 15) * 64, y0 = (rem >> 4) * 64;
  const float* W = (z == 0) ? w0 : (z == 1) ? w1 : (z == 2) ? w2 : w3;
  u16* Wt = wt + (size_t)z * 1048576u;
  const int tx = threadIdx.x & 63, ty = threadIdx.x >> 6;  // 64 x 4
#pragma unroll
  for (int j = 0; j < 16; ++j)
    tile[ty + j * 4][tx] = W[(size_t)(y0 + ty + j * 4) * 1024 + x0 + tx];
  __syncthreads();
#pragma unroll
  for (int j = 0; j < 16; ++j)
    Wt[(size_t)(x0 + ty + j * 4) * 1024 + y0 + tx] = f2bf(tile[tx][ty + j * 4]);
}

// ---------------- merged projection GEMM (Q, K, V^T) ----------------
// z=0: Qb = (Xq @ Wq + bq) * qsc        [4096][1024]
// z=1: Kb =  Xk @ Wk + bk               [4096][1024]
// z=2: VtG = (Wv^T . Xv^T) + bv(row)    [1024][4096]
// Two-barrier loop (R7 dbuf regressed: compiler drains vmcnt before ds_read).
// launch_bounds(256,3): cap VGPR at 170 -> guaranteed 3 blocks/CU (m97-class).
__global__ __launch_bounds__(256, 3) void gemm_proj(
    const u16* __restrict__ Xb, const u16* __restrict__ Wt,
    const float* __restrict__ bqp, const float* __restrict__ bkp,
    const float* __restrict__ bvp,
    u16* __restrict__ Qb, u16* __restrict__ Kb, u16* __restrict__ VtG,
    float qsc) {
  const int z = blockIdx.z;
  const u16 *A, *Bt;
  const float* bias;
  u16* C;
  int N, bm, bn;
  float osc = 1.f;
  bool rowb = false;
  if (z < 2) {
    A = Xb + (size_t)z * 4194304u;
    Bt = Wt + (size_t)z * 1048576u;
    bias = z ? bkp : bqp;
    C = z ? Kb : Qb;
    N = 1024;
    bm = blockIdx.x * 128;
    bn = blockIdx.y * 128;
    if (z == 0) osc = qsc;
  } else {
    A = Wt + 2u * 1048576u;
    Bt = Xb + 2u * 4194304u;
    bias = bvp;
    C = VtG;
    N = 4096;
    bm = blockIdx.y * 128;
    bn = blockIdx.x * 128;
    rowb = true;
  }

  __shared__ __align__(16) u16 ldsA[128 * 64];
  __shared__ __align__(16) u16 ldsB[128 * 64];

  const int tid = threadIdx.x;
  const int lane = tid & 63, wv = tid >> 6;
  const int wr = wv >> 1, wc = wv & 1;
  const int l15 = lane & 15, l4 = lane >> 4;

  const f32x4 zero4 = {0.f, 0.f, 0.f, 0.f};
  f32x4 acc[4][4];
#pragma unroll
  for (int i = 0; i < 4; ++i)
#pragma unroll
    for (int j = 0; j < 4; ++j) acc[i][j] = zero4;

  for (int kt = 0; kt < 16; ++kt) {
    __syncthreads();
#pragma unroll
    for (int g = 0; g < 4; ++g) {
      int p = g * 256 + tid;
      int row = p >> 3;
      int ss = (p & 7) ^ (row & 7);
      gload16(A + (size_t)(bm + row) * 1024 + kt * 64 + ss * 8,
              (char*)ldsA + (g * 256 + wv * 64) * 16);
    }
#pragma unroll
    for (int g = 0; g < 4; ++g) {
      int p = g * 256 + tid;
      int row = p >> 3;
      int ss = (p & 7) ^ (row & 7);
      gload16(Bt + (size_t)(bn + row) * 1024 + kt * 64 + ss * 8,
              (char*)ldsB + (g * 256 + wv * 64) * 16);
    }
    __syncthreads();

    bf16x8 af[4][2], bfr[4][2];
#pragma unroll
    for (int mf = 0; mf < 4; ++mf) {
      int row = wr * 64 + mf * 16 + l15;
#pragma unroll
      for (int ks = 0; ks < 2; ++ks) {
        int byt = row * 128 + ((ks * 64 + l4 * 16) ^ ((row & 7) << 4));
        af[mf][ks] = *(const bf16x8*)((const char*)ldsA + byt);
      }
    }
#pragma unroll
    for (int nf = 0; nf < 4; ++nf) {
      int row = wc * 64 + nf * 16 + l15;
#pragma unroll
      for (int ks = 0; ks < 2; ++ks) {
        int byt = row * 128 + ((ks * 64 + l4 * 16) ^ ((row & 7) << 4));
        bfr[nf][ks] = *(const bf16x8*)((const char*)ldsB + byt);
      }
    }
#pragma unroll
    for (int mf = 0; mf < 4; ++mf)
#pragma unroll
      for (int nf = 0; nf < 4; ++nf) {
        acc[mf][nf] = __builtin_amdgcn_mfma_f32_16x16x32_bf16(
            af[mf][0], bfr[nf][0], acc[mf][nf], 0, 0, 0);
        acc[mf][nf] = __builtin_amdgcn_mfma_f32_16x16x32_bf16(
            af[mf][1], bfr[nf][1], acc[mf][nf], 0, 0, 0);
      }
  }

  float bcol[4];
  if (!rowb) {
#pragma unroll
    for (int nf = 0; nf < 4; ++nf)
      bcol[nf] = bias[bn + wc * 64 + nf * 16 + l15];
  }
#pragma unroll
  for (int mf = 0; mf < 4; ++mf) {
#pragma unroll
    for (int i = 0; i < 4; ++i) {
      int r = bm + wr * 64 + mf * 16 + l4 * 4 + i;
      float br = rowb ? bias[r] : 0.f;
#pragma unroll
      for (int nf = 0; nf < 4; ++nf) {
        int c = bn + wc * 64 + nf * 16 + l15;
        float val = (acc[mf][nf][i] + (rowb ? br : bcol[nf])) * osc;
        C[(size_t)r * N + c] = f2bf(val);
      }
    }
  }
}

// ---------------- final GEMM: out = ctx @ Wo^T' + bo (fp32) ----------------
__global__ __launch_bounds__(256, 3) void gemm_out(
    const u16* __restrict__ A, const u16* __restrict__ Bt,
    const float* __restrict__ bias, float* __restrict__ C) {
  __shared__ __align__(16) u16 ldsA[128 * 64];
  __shared__ __align__(16) u16 ldsB[128 * 64];

  const int tid = threadIdx.x;
  const int lane = tid & 63, wv = tid >> 6;
  const int wr = wv >> 1, wc = wv & 1;
  const int l15 = lane & 15, l4 = lane >> 4;
  const int bm = blockIdx.x * 128, bn = blockIdx.y * 128;

  const f32x4 zero4 = {0.f, 0.f, 0.f, 0.f};
  f32x4 acc[4][4];
#pragma unroll
  for (int i = 0; i < 4; ++i)
#pragma unroll
    for (int j = 0; j < 4; ++j) acc[i][j] = zero4;

  for (int kt = 0; kt < 16; ++kt) {
    __syncthreads();
#pragma unroll
    for (int g = 0; g < 4; ++g) {
      int p = g * 256 + tid;
      int row = p >> 3;
      int ss = (p & 7) ^ (row & 7);
      gload16(A + (size_t)(bm + row) * 1024 + kt * 64 + ss * 8,
              (char*)ldsA + (g * 256 + wv * 64) * 16);
    }
#pragma unroll
    for (int g = 0; g < 4; ++g) {
      int p = g * 256 + tid;
      int row = p >> 3;
      int ss = (p & 7) ^ (row & 7);
      gload16(Bt + (size_t)(bn + row) * 1024 + kt * 64 + ss * 8,
              (char*)ldsB + (g * 256 + wv * 64) * 16);
    }
    __syncthreads();

    bf16x8 af[4][2], bfr[4][2];
#pragma unroll
    for (int mf = 0; mf < 4; ++mf) {
      int row = wr * 64 + mf * 16 + l15;
#pragma unroll
      for (int ks = 0; ks < 2; ++ks) {
        int byt = row * 128 + ((ks * 64 + l4 * 16) ^ ((row & 7) << 4));
        af[mf][ks] = *(const bf16x8*)((const char*)ldsA + byt);
      }
    }
#pragma unroll
    for (int nf = 0; nf < 4; ++nf) {
      int row = wc * 64 + nf * 16 + l15;
#pragma unroll
      for (int ks = 0; ks < 2; ++ks) {
        int byt = row * 128 + ((ks * 64 + l4 * 16) ^ ((row & 7) << 4));
        bfr[nf][ks] = *(const bf16x8*)((const char*)ldsB + byt);
      }
    }
#pragma unroll
    for (int mf = 0; mf < 4; ++mf)
#pragma unroll
      for (int nf = 0; nf < 4; ++nf) {
        acc[mf][nf] = __builtin_amdgcn_mfma_f32_16x16x32_bf16(
            af[mf][0], bfr[nf][0], acc[mf][nf], 0, 0, 0);
        acc[mf][nf] = __builtin_amdgcn_mfma_f32_16x16x32_bf16(
            af[mf][1], bfr[nf][1], acc[mf][nf], 0, 0, 0);
      }
  }

  float bcol[4];
#pragma unroll
  for (int nf = 0; nf < 4; ++nf)
    bcol[nf] = bias[bn + wc * 64 + nf * 16 + l15];
#pragma unroll
  for (int mf = 0; mf < 4; ++mf) {
#pragma unroll
    for (int i = 0; i < 4; ++i) {
      int r = bm + wr * 64 + mf * 16 + l4 * 4 + i;
#pragma unroll
      for (int nf = 0; nf < 4; ++nf) {
        int c = bn + wc * 64 + nf * 16 + l15;
        C[(size_t)r * 1024 + c] = acc[mf][nf][i] + bcol[nf];
      }
    }
  }
}

// ---------------- causal flash attention (R6 body, proven 50.5 us) ---------
// Swapped QK^T, KVBLK=64, XCD-pinned columns, 4 blocks/CU, single-barrier
// double buffering, defer-max, per-wave P via LDS.
__global__ __launch_bounds__(256, 4) void attn_k(
    const u16* __restrict__ Q, const u16* __restrict__ Kb,
    const u16* __restrict__ Vt, u16* __restrict__ ctx) {
  const int id = blockIdx.x + (blockIdx.y << 5);
  const int xcd = id & 7;
  const int kk = id >> 3;               // 0..127
  const int bh = xcd * 4 + (kk & 3);    // 4 bh columns per XCD
  const int qt = 31 - (kk >> 2);        // q-tile, longest first
  const int b = bh >> 4, h = bh & 15;
  const int tid = threadIdx.x;
  const int lane = tid & 63, wv = tid >> 6;
  const int l15 = lane & 15, l4 = lane >> 4;

  __shared__ __align__(16) u16 Kt[2][64 * 64];   // [kv][d], swizzled
  __shared__ __align__(16) u16 Vl[2][64 * 64];   // [d][kv], swizzled
  __shared__ __align__(16) u16 Pl[4][16 * 64];   // per-wave P [q][kv], swizzled

  const u16* KB = Kb + (size_t)(b * 2048) * 1024 + h * 64;
  const u16* VB = Vt + (size_t)(h * 64) * 4096 + b * 2048;

  const u16* qp =
      Q + (size_t)(b * 2048 + qt * 64 + wv * 16 + l15) * 1024 + h * 64;
  bf16x8 qf0 = *(const bf16x8*)(qp + l4 * 8);
  bf16x8 qf1 = *(const bf16x8*)(qp + 32 + l4 * 8);

  const f32x4 zero4 = {0.f, 0.f, 0.f, 0.f};
  f32x4 oacc[4];  // [nt]: O[q=l4*4+i][d=nt*16+l15]
#pragma unroll
  for (int i = 0; i < 4; ++i) oacc[i] = zero4;
  float m = -1e30f, lsum = 0.f;  // per-lane softmax state for q = l15

  auto issueKV = [&](int jt, int bufi) {
    const u16* kb = KB + (size_t)(jt * 64) * 1024;
#pragma unroll
    for (int g = 0; g < 2; ++g) {
      int p = g * 256 + tid;
      int row = p >> 3;
      int ss = (p & 7) ^ (row & 7);
      gload16(kb + (size_t)row * 1024 + ss * 8,
              (char*)(&Kt[bufi][0]) + (g * 256 + wv * 64) * 16);
    }
#pragma unroll
    for (int g = 0; g < 2; ++g) {
      int p = g * 256 + tid;
      int d = p >> 3;
      int ss = (p & 7) ^ (d & 7);
      gload16(VB + (size_t)d * 4096 + jt * 64 + ss * 8,
              (char*)(&Vl[bufi][0]) + (g * 256 + wv * 64) * 16);
    }
  };

  issueKV(0, 0);
  for (int j = 0; j <= qt; ++j) {
    const int cur = j & 1;
    __syncthreads();  // own-vmcnt drain -> tile j in LDS; frees other buffer
    if (j < qt) issueKV(j + 1, cur ^ 1);

    // S^T tiles: rows kv, cols q  (A = K-frag, B = Q-frag)
    f32x4 p4[4];
    __builtin_amdgcn_s_setprio(1);
#pragma unroll
    for (int nt = 0; nt < 4; ++nt) {
      int row = nt * 16 + l15;
      int sw = (row & 7) << 4;
      const char* kr = (const char*)&Kt[cur][0] + row * 128;
      bf16x8 k0 = *(const bf16x8*)(kr + ((l4 * 16) ^ sw));
      bf16x8 k1 = *(const bf16x8*)(kr + ((64 + l4 * 16) ^ sw));
      f32x4 s = zero4;
      s = __builtin_amdgcn_mfma_f32_16x16x32_bf16(k0, qf0, s, 0, 0, 0);
      s = __builtin_amdgcn_mfma_f32_16x16x32_bf16(k1, qf1, s, 0, 0, 0);
      p4[nt] = s;
    }
    __builtin_amdgcn_s_setprio(0);

    if (j == qt) {  // causal mask on diagonal tile: kv_local > q_local
#pragma unroll
      for (int nt = 0; nt < 4; ++nt)
#pragma unroll
        for (int i = 0; i < 4; ++i)
          if (nt * 16 + l4 * 4 + i > wv * 16 + l15) p4[nt][i] = -1e30f;
    }

    // row max: 16 in-register + 2 cross-lane steps (l4 dim)
    float rm = p4[0][0];
#pragma unroll
    for (int nt = 0; nt < 4; ++nt)
#pragma unroll
      for (int i = 0; i < 4; ++i) rm = fmaxf(rm, p4[nt][i]);
    rm = fmaxf(rm, __shfl_xor(rm, 16, 64));
    rm = fmaxf(rm, __shfl_xor(rm, 32, 64));

    // defer-max (THR=8 in log2 domain): rescale only when max grew
    if (!__all(rm - m <= 8.0f)) {
      float mn = fmaxf(m, rm);
      float ce = exp2f(m - mn);
      m = mn;
      lsum *= ce;
#pragma unroll
      for (int i = 0; i < 4; ++i) {
        float cei = __shfl(ce, (lane & 48) | (l4 * 4 + i), 64);
#pragma unroll
        for (int nt = 0; nt < 4; ++nt) oacc[nt][i] *= cei;
      }
    }

    // P = exp2(S - m), row-sum
    float rs = 0.f;
#pragma unroll
    for (int nt = 0; nt < 4; ++nt)
#pragma unroll
      for (int i = 0; i < 4; ++i) {
        float e = exp2f(p4[nt][i] - m);
        p4[nt][i] = e;
        rs += e;
      }
    rs += __shfl_xor(rs, 16, 64);
    rs += __shfl_xor(rs, 32, 64);
    lsum += rs;

    // P -> Pl[wv] as [q=16][kv=64] bf16: 4 x ds_write_b64 (kv contiguous)
    {
      int sw = (l15 & 7) << 4;
#pragma unroll
      for (int nt = 0; nt < 4; ++nt) {
        bf16x4 pb = __builtin_convertvector(p4[nt], bf16x4);
        *(bf16x4*)((char*)&Pl[wv][0] + l15 * 128 + ((nt * 32 + l4 * 8) ^ sw)) = pb;
      }
    }

    // O += P V
    bf16x8 pa0, pa1;
    {
      int sw = (l15 & 7) << 4;
      pa0 = *(const bf16x8*)((const char*)&Pl[wv][0] + l15 * 128 + ((l4 * 16) ^ sw));
      pa1 = *(const bf16x8*)((const char*)&Pl[wv][0] + l15 * 128 +
                             ((64 + l4 * 16) ^ sw));
    }
    __builtin_amdgcn_s_setprio(1);
#pragma unroll
    for (int nt = 0; nt < 4; ++nt) {
      int d = nt * 16 + l15;
      int sw = (d & 7) << 4;
      const char* vr = (const char*)&Vl[cur][0] + d * 128;
      bf16x8 v0 = *(const bf16x8*)(vr + ((l4 * 16) ^ sw));
      bf16x8 v1 = *(const bf16x8*)(vr + ((64 + l4 * 16) ^ sw));
      oacc[nt] = __builtin_amdgcn_mfma_f32_16x16x32_bf16(pa0, v0, oacc[nt], 0, 0, 0);
      oacc[nt] = __builtin_amdgcn_mfma_f32_16x16x32_bf16(pa1, v1, oacc[nt], 0, 0, 0);
    }
    __builtin_amdgcn_s_setprio(0);
  }

  // normalize + store ctx (bf16, [b*2048+q][h*64+d])
  float rcp = 1.f / lsum;
  u16* cb = ctx + (size_t)(b * 2048 + qt * 64 + wv * 16) * 1024 + h * 64;
#pragma unroll
  for (int i = 0; i < 4; ++i) {
    float iv = __shfl(rcp, (lane & 48) | (l4 * 4 + i), 64);
    int r = l4 * 4 + i;
#pragma unroll
    for (int nt = 0; nt < 4; ++nt)
      cb[(size_t)r * 1024 + nt * 16 + l15] = f2bf(oacc[nt][i] * iv);
  }
}

// ---------------- launch ----------------
extern "C" void kernel_launch(void* const* d_in, const int* in_sizes, int n_in,
                              void* d_out, int out_size, void* d_ws,
                              size_t ws_size, hipStream_t stream) {
  const float* q  = (const float*)d_in[0];
  const float* k  = (const float*)d_in[1];
  const float* v  = (const float*)d_in[2];
  const float* Wq = (const float*)d_in[3];
  const float* bq = (const float*)d_in[4];
  const float* Wk = (const float*)d_in[5];
  const float* bk = (const float*)d_in[6];
  const float* Wv = (const float*)d_in[7];
  const float* bv = (const float*)d_in[8];
  const float* Wo = (const float*)d_in[9];
  const float* bo = (const float*)d_in[10];

  // workspace layout (40 MiB):
  //   [0,24M):   Xb = bf16(query|key|value); first 8 MiB reused later as ctx
  //   [24M,32M): Wt = bf16 W^T for q,k,v,o
  //   [32M,40M): VtG = V^T bf16 [1024][4096]
  // d_out (16 MiB) doubles as Qb|Kb bf16 scratch until the final GEMM
  // fully overwrites it with fp32 output (deterministic each call).
  char* ws = (char*)d_ws;
  u16* Xb  = (u16*)ws;
  u16* Wt  = (u16*)(ws + 25165824);
  u16* VtG = (u16*)(ws + 33554432);
  u16* ctx = Xb;
  u16* Qb  = (u16*)d_out;
  u16* Kb  = Qb + 4194304;

  const float SC2A = 0.0318793585f;  // log2(e)/sqrt(2048), folded into Q

  prep_k<<<dim3(7168), 256, 0, stream>>>(q, k, v, Xb, Wq, Wk, Wv, Wo, Wt);
  gemm_proj<<<dim3(32, 8, 3), 256, 0, stream>>>(Xb, Wt, bq, bk, bv, Qb, Kb,
                                                VtG, SC2A);
  attn_k<<<dim3(32, 32), 256, 0, stream>>>(Qb, Kb, VtG, ctx);
  gemm_out<<<dim3(32, 8), 256, 0, stream>>>(ctx, Wt + 3 * 1048576, bo,
                                            (float*)d_out);
}